// Round 1
// baseline (13393.842 us; speedup 1.0000x reference)
//
#include <hip/hip_runtime.h>
#include <cmath>

// Problem constants
//   B=64, T=12, N=512, HORIZON=12, RNN=64, MEM_NUM=20, MEM_DIM=64, EMB=10,
//   CHEB_K=3, DEC_DIM=128
// Encoder: HC=64 h-cols, NEX=1 extra (x), SEGW=68 (padded), K=204, BB=128 (x & x_his stacked)
// Decoder: HC=128, NEX=2 (go,ycov), SEGW=132, K=396, BB=64

// ---------------- zero fill ----------------
__global__ void k_zero(float* __restrict__ p, int n){
  int i = blockIdx.x*256 + threadIdx.x;
  if (i < n) p[i] = 0.f;
}

// ---------------- W reorder: ref order per cheb seg = [extras(NEX), h(HC)] -> my [h, extras, pad0] ----------------
__global__ void k_reorder(const float* __restrict__ W, float* __restrict__ Wr,
                          int HC, int NEX, int SEGW, int J){
  int idx = blockIdx.x*256 + threadIdx.x;
  int K = 3*SEGW;
  if (idx >= K*J) return;
  int k = idx / J, j = idx - k*J;
  int seg = k / SEGW, c = k - seg*SEGW;
  int CIN = HC + NEX;
  float v = 0.f;
  if (c < HC)       v = W[(size_t)(seg*CIN + NEX + c)*J + j];
  else if (c < CIN) v = W[(size_t)(seg*CIN + (c-HC))*J + j];
  Wr[(size_t)k*J + j] = v;
}

// ---------------- pack seg0 = [h | extras | 0], zero pads of seg1/seg2 ----------------
template<int HC,int NEX,int SEGW>
__global__ void k_pack(const float* __restrict__ hsrc,
                       const float* __restrict__ e0a, const float* __restrict__ e0b, int e0bbs,
                       const float* __restrict__ e1, int e1bbs,
                       float* __restrict__ feats, int total){
  const int FS = 3*SEGW;
  int idx = blockIdx.x*256 + threadIdx.x;
  if (idx >= total) return;
  int row = idx / SEGW, c = idx - row*SEGW;
  float v;
  if (c < HC) v = hsrc[(size_t)row*HC + c];
  else if (c < HC+NEX){
    int bb = row >> 9, m = row & 511;
    if (c == HC) v = (bb < 64) ? e0a[(size_t)bb*e0bbs + m] : e0b[(size_t)(bb-64)*e0bbs + m];
    else         v = e1[(size_t)bb*e1bbs + m];
  } else {
    v = 0.f;
    feats[(size_t)row*FS + SEGW   + c] = 0.f;
    feats[(size_t)row*FS + 2*SEGW + c] = 0.f;
  }
  feats[(size_t)row*FS + c] = v;
}

// ---------------- batched graph matmul: OUTseg = alpha * M_bb @ Xseg + beta * Yseg ----------------
// M: (512,512) per bb (stride mbbs; 0 => shared). X/Y/OUT: segments of feats, row stride FS=3*SEGW.
// Block: 128 rows x 64 cols tile, 256 threads, TM=8 x TN=4. Extras (cols HC..HC+NEX-1) by blockIdx.y==0.
template<int HC,int NEX,int SEGW>
__global__ __launch_bounds__(256) void k_mm(
    const float* __restrict__ M, long long mbbs,
    float* __restrict__ feats, int xseg, int oseg, int yseg,
    float alpha, float beta){
  const int FS = 3*SEGW;
  int t = threadIdx.x;
  int bb = blockIdx.z;
  int n0 = blockIdx.x * 128;
  int c0 = blockIdx.y * 64;
  const float* Mb = M + (size_t)bb * mbbs;
  const float* Xb = feats + (size_t)bb*512*FS + xseg;
  const float* Yb = feats + (size_t)bb*512*FS + yseg;
  float*       Ob = feats + (size_t)bb*512*FS + oseg;
  __shared__ float Ms[32][132];  // [k][row], transposed, padded
  __shared__ float Bs[32][68];   // [k][col 0..63 | extras 64..]
  int tr = t & 15, tc = t >> 4;
  float acc[8][4];
  #pragma unroll
  for (int i=0;i<8;i++){
    #pragma unroll
    for (int c=0;c<4;c++) acc[i][c] = 0.f;
  }
  float acce[NEX];
  #pragma unroll
  for (int j=0;j<NEX;j++) acce[j]=0.f;
  const bool doe = (blockIdx.y==0) && (t < 128);
  for (int k0=0;k0<512;k0+=32){
    #pragma unroll
    for (int i=0;i<4;i++){
      int s = t + i*256;
      int r = s >> 3, kq = s & 7;
      const float4 v = *(const float4*)(Mb + (size_t)(n0+r)*512 + k0 + kq*4);
      Ms[kq*4+0][r]=v.x; Ms[kq*4+1][r]=v.y; Ms[kq*4+2][r]=v.z; Ms[kq*4+3][r]=v.w;
    }
    #pragma unroll
    for (int i=0;i<2;i++){
      int s = t + i*256;
      int k = s >> 4, cq = s & 15;
      const float4 v = *(const float4*)(Xb + (size_t)(k0+k)*FS + c0 + cq*4);
      *(float4*)&Bs[k][cq*4] = v;
    }
    if (blockIdx.y==0 && t < 32*NEX){
      int k = t & 31, j = t >> 5;
      Bs[k][64+j] = Xb[(size_t)(k0+k)*FS + HC + j];
    }
    __syncthreads();
    #pragma unroll 8
    for (int k=0;k<32;k++){
      float4 a0 = *(const float4*)&Ms[k][tr*8];
      float4 a1 = *(const float4*)&Ms[k][tr*8+4];
      float4 b  = *(const float4*)&Bs[k][tc*4];
      float av[8] = {a0.x,a0.y,a0.z,a0.w,a1.x,a1.y,a1.z,a1.w};
      float bv[4] = {b.x,b.y,b.z,b.w};
      #pragma unroll
      for (int i=0;i<8;i++){
        #pragma unroll
        for (int c=0;c<4;c++) acc[i][c] += av[i]*bv[c];
      }
    }
    if (doe){
      #pragma unroll 8
      for (int k=0;k<32;k++){
        float av = Ms[k][t];
        #pragma unroll
        for (int j=0;j<NEX;j++) acce[j] += av * Bs[k][64+j];
      }
    }
    __syncthreads();
  }
  #pragma unroll
  for (int i=0;i<8;i++){
    int rr = n0 + tr*8 + i;
    float4 o;
    o.x = alpha*acc[i][0]; o.y = alpha*acc[i][1]; o.z = alpha*acc[i][2]; o.w = alpha*acc[i][3];
    if (beta != 0.f){
      const float4 y = *(const float4*)(Yb + (size_t)rr*FS + c0 + tc*4);
      o.x += beta*y.x; o.y += beta*y.y; o.z += beta*y.z; o.w += beta*y.w;
    }
    *(float4*)(Ob + (size_t)rr*FS + c0 + tc*4) = o;
  }
  if (doe){
    #pragma unroll
    for (int j=0;j<NEX;j++){
      float ov = alpha*acce[j];
      if (beta != 0.f) ov += beta * Yb[(size_t)(n0+t)*FS + HC + j];
      Ob[(size_t)(n0+t)*FS + HC + j] = ov;
    }
  }
}

// ---------------- feats @ Wr (+bias) with fused gate / update epilogue ----------------
// MODE 0 (gate): s=sigmoid(.); j<Hdim -> zh=s*h ; else r=s
// MODE 1 (upd):  hc=tanh(.); hout = r*h + (1-r)*hc   (in-place on h allowed)
template<int K,int KC,int JT,int TN,int Hdim,int MODE>
__global__ __launch_bounds__(256) void k_gw(
    const float* __restrict__ feats, const float* __restrict__ Wr,
    const float* __restrict__ bias, int Jtot,
    const float* __restrict__ hbuf, float* __restrict__ outp, float* __restrict__ rbuf){
  __shared__ float As[KC][68];   // [k][row], rows 0..63
  __shared__ float Ws[KC][JT];
  int t = threadIdx.x;
  int row0 = blockIdx.x*64, j0 = blockIdx.y*JT;
  int tr = t & 15, tc = t >> 4;
  float acc[4][TN];
  #pragma unroll
  for (int i=0;i<4;i++){
    #pragma unroll
    for (int j=0;j<TN;j++) acc[i][j]=0.f;
  }
  for (int kc0=0; kc0<K; kc0+=KC){
    for (int s=t; s<64*KC; s+=256){
      int r = s / KC, k = s - r*KC;
      As[k][r] = feats[(size_t)(row0+r)*K + kc0 + k];
    }
    for (int s=t; s<KC*JT; s+=256){
      int k = s / JT, j = s - k*JT;
      Ws[k][j] = Wr[(size_t)(kc0+k)*Jtot + j0 + j];
    }
    __syncthreads();
    #pragma unroll 4
    for (int k=0;k<KC;k++){
      float4 a = *(const float4*)&As[k][tr*4];
      float av[4] = {a.x,a.y,a.z,a.w};
      #pragma unroll
      for (int jj=0;jj<TN;jj+=4){
        float4 w = *(const float4*)&Ws[k][tc*TN+jj];
        float wv[4] = {w.x,w.y,w.z,w.w};
        #pragma unroll
        for (int i=0;i<4;i++){
          #pragma unroll
          for (int c=0;c<4;c++) acc[i][jj+c] += av[i]*wv[c];
        }
      }
    }
    __syncthreads();
  }
  #pragma unroll
  for (int i=0;i<4;i++){
    int row = row0 + tr*4 + i;
    #pragma unroll
    for (int jj=0;jj<TN;jj++){
      int j = j0 + tc*TN + jj;
      float xv = acc[i][jj] + bias[j];
      if (MODE == 0){
        float s = 1.f/(1.f + __expf(-xv));
        if (j < Hdim) outp[(size_t)row*Hdim + j] = s * hbuf[(size_t)row*Hdim + j];
        else          rbuf[(size_t)row*Hdim + (j-Hdim)] = s;
      } else {
        float hc = 1.f - 2.f/(__expf(2.f*xv) + 1.f);   // tanh, overflow-safe
        float rr = rbuf[(size_t)row*Hdim + j];
        outp[(size_t)row*Hdim + j] = rr*hbuf[(size_t)row*Hdim + j] + (1.f-rr)*hc;
      }
    }
  }
}

// ---------------- memory query: q=h@Wq, att=softmax(q@Mem^T), value=att@Mem, argmax ----------------
__global__ __launch_bounds__(256) void k_query(const float* __restrict__ he,
      const float* __restrict__ Wq, const float* __restrict__ Mem,
      float* __restrict__ haug, int* __restrict__ it, int* __restrict__ ih){
  int sub = threadIdx.x >> 6, lane = threadIdx.x & 63;
  int row = blockIdx.x*4 + sub;          // bb*512+n, bb<128
  __shared__ float sh[4][64], sq[4][64], ss[4][20];
  float hv = he[(size_t)row*64 + lane];
  sh[sub][lane] = hv;
  __syncthreads();
  float q = 0.f;
  for (int c=0;c<64;c++) q += sh[sub][c]*Wq[c*64 + lane];
  sq[sub][lane] = q;
  __syncthreads();
  if (lane < 20){
    float s = 0.f;
    for (int j=0;j<64;j++) s += sq[sub][j]*Mem[lane*64 + j];
    ss[sub][lane] = s;
  }
  __syncthreads();
  float mx = -1e30f; int am = 0;
  for (int m=0;m<20;m++){ float s = ss[sub][m]; if (s > mx){ mx = s; am = m; } }
  float sum = 0.f;
  for (int m=0;m<20;m++) sum += __expf(ss[sub][m]-mx);
  float inv = 1.f/sum;
  float v = 0.f;
  for (int m=0;m<20;m++) v += __expf(ss[sub][m]-mx)*inv*Mem[m*64 + lane];
  int bb = row >> 9;
  if (bb < 64){
    haug[(size_t)row*128 + lane]      = hv;
    haug[(size_t)row*128 + 64 + lane] = v;
    if (lane==0) it[row] = am;
  } else {
    if (lane==0) ih[row - 32768] = am;
  }
}

// ---------------- latent_dis = sigmoid((Mem[i1]-Mem[i2]) @ lat_W + b) ----------------
__global__ void k_latent(const int* __restrict__ it, const int* __restrict__ ih,
                         const float* __restrict__ Mem,
                         const float* __restrict__ lW, const float* __restrict__ lb,
                         float* __restrict__ outl){
  int row = blockIdx.x*256 + threadIdx.x;  // 32768
  int i1 = it[row], i2 = ih[row];
  float a = lb[0];
  for (int c=0;c<64;c++) a += (Mem[i1*64+c]-Mem[i2*64+c])*lW[c];
  outl[row] = 1.f/(1.f + __expf(-a));
}

// ---------------- node_emb = h_aug @ hyper_W + hyper_b ----------------
__global__ void k_emb(const float* __restrict__ haug, const float* __restrict__ hW,
                      const float* __restrict__ hb, float* __restrict__ emb){
  int idx = blockIdx.x*256 + threadIdx.x;
  int row = idx >> 4, e = idx & 15;
  if (row < 32768 && e < 10){
    float a = hb[e];
    for (int c=0;c<128;c++) a += haug[(size_t)row*128+c]*hW[c*10+e];
    emb[(size_t)row*10+e] = a;
  }
}

// ---------------- support[b,n,:] = softmax(relu(emb[b,n]·emb[b,m])) ----------------
__global__ __launch_bounds__(256) void k_support(const float* __restrict__ emb,
                                                 float* __restrict__ sup){
  int b = blockIdx.x >> 9;
  int n = blockIdx.x & 511;
  int t = threadIdx.x;
  __shared__ float se[5120];
  __shared__ float red[8];
  for (int s = t; s < 5120; s += 256) se[s] = emb[(size_t)b*5120 + s];
  __syncthreads();
  float en[10];
  #pragma unroll
  for (int i=0;i<10;i++) en[i] = se[n*10+i];
  float s0=0.f, s1=0.f;
  #pragma unroll
  for (int i=0;i<10;i++){ s0 += en[i]*se[t*10+i]; s1 += en[i]*se[(t+256)*10+i]; }
  s0 = fmaxf(s0, 0.f); s1 = fmaxf(s1, 0.f);
  float mx = fmaxf(s0, s1);
  for (int o=32;o>0;o>>=1) mx = fmaxf(mx, __shfl_down(mx, o));
  if ((t&63)==0) red[t>>6] = mx;
  __syncthreads();
  mx = fmaxf(fmaxf(red[0],red[1]), fmaxf(red[2],red[3]));
  float e0 = __expf(s0-mx), e1 = __expf(s1-mx);
  float sm = e0 + e1;
  for (int o=32;o>0;o>>=1) sm += __shfl_down(sm, o);
  if ((t&63)==0) red[4+(t>>6)] = sm;
  __syncthreads();
  sm = red[4]+red[5]+red[6]+red[7];
  float inv = 1.f/sm;
  size_t base = ((size_t)b*512 + n)*512;
  sup[base + t]       = e0*inv;
  sup[base + t + 256] = e1*inv;
}

// ---------------- projection: go = h@proj_W + b; also write output[b,t,n] ----------------
__global__ __launch_bounds__(256) void k_proj(const float* __restrict__ h,
      const float* __restrict__ pW, const float* __restrict__ pb,
      float* __restrict__ go, float* __restrict__ out, int tstep){
  int sub = threadIdx.x >> 6, lane = threadIdx.x & 63;
  int row = blockIdx.x*4 + sub;  // b*512+n
  float a = h[(size_t)row*128 + lane]*pW[lane] + h[(size_t)row*128 + 64 + lane]*pW[64+lane];
  for (int o=32;o>0;o>>=1) a += __shfl_down(a, o);
  if (lane == 0){
    a += pb[0];
    go[row] = a;
    int b = row >> 9, n = row & 511;
    out[((size_t)b*12 + tstep)*512 + n] = a;
  }
}

extern "C" void kernel_launch(void* const* d_in, const int* in_sizes, int n_in,
                              void* d_out, int out_size, void* d_ws, size_t ws_size,
                              hipStream_t stream) {
  const float* x     = (const float*)d_in[0];
  // d_in[1] = x_cov (unused by reference)
  const float* x_his = (const float*)d_in[2];
  const float* y_cov = (const float*)d_in[3];
  const float* adj   = (const float*)d_in[4];
  const float* egW   = (const float*)d_in[5];
  const float* egb   = (const float*)d_in[6];
  const float* euW   = (const float*)d_in[7];
  const float* eub   = (const float*)d_in[8];
  const float* dgW   = (const float*)d_in[9];
  const float* dgb   = (const float*)d_in[10];
  const float* duW   = (const float*)d_in[11];
  const float* dub   = (const float*)d_in[12];
  const float* Mem   = (const float*)d_in[13];
  const float* Wq    = (const float*)d_in[14];
  const float* hW    = (const float*)d_in[15];
  const float* hb    = (const float*)d_in[16];
  const float* lW    = (const float*)d_in[17];
  const float* lb    = (const float*)d_in[18];
  const float* pW    = (const float*)d_in[19];
  const float* pb    = (const float*)d_in[20];
  float* out  = (float*)d_out;           // (64,12,512,1) flat
  float* outl = out + 393216;            // (64,512) flat

  float* ws = (float*)d_ws;
  size_t off = 0;
  auto alloc = [&](size_t nfl){ float* p = ws + off; off += nfl; return p; };
  float* feats = alloc(13369344);  // max(128*512*204, 64*512*396)
  float* zh    = alloc(4194304);   // enc 128*512*64 / dec 64*512*128
  float* rb    = alloc(4194304);
  float* henc  = alloc(4194304);   // (128,512,64) encoder states (x | x_his)
  float* haug  = alloc(4194304);   // (64,512,128) h_aug, then decoder state
  float* sup   = alloc(16777216);  // (64,512,512)
  float* emb   = alloc(327680);    // (64,512,10)
  float* go    = alloc(32768);
  int*   it    = (int*)alloc(32768);
  int*   ih    = (int*)alloc(32768);
  float* wr_eg = alloc(204*128);
  float* wr_eu = alloc(204*64);
  float* wr_dg = alloc(396*256);
  float* wr_du = alloc(396*128);
  if (ws_size < off*sizeof(float)) return;  // workspace too small -> visible failure

  // one-time per launch
  k_zero<<<16384,256,0,stream>>>(henc, 4194304);
  k_zero<<<128,  256,0,stream>>>(go, 32768);
  k_reorder<<<(204*128+255)/256,256,0,stream>>>(egW, wr_eg, 64,1,68,128);
  k_reorder<<<(204*64 +255)/256,256,0,stream>>>(euW, wr_eu, 64,1,68,64);
  k_reorder<<<(396*256+255)/256,256,0,stream>>>(dgW, wr_dg, 128,2,132,256);
  k_reorder<<<(396*128+255)/256,256,0,stream>>>(duW, wr_du, 128,2,132,128);

  // ---------------- encoders (x and x_his together, BB=128) ----------------
  const int encPack = 128*512*68;
  for (int t = 0; t < 12; t++){
    const float* e0a = x + t*512;
    const float* e0b = x_his + t*512;
    k_pack<64,1,68><<<(encPack+255)/256,256,0,stream>>>(henc, e0a, e0b, 6144, nullptr, 0, feats, encPack);
    k_mm<64,1,68><<<dim3(4,1,128),256,0,stream>>>(adj, 0, feats, 0,  68, 0, 1.f,  0.f);
    k_mm<64,1,68><<<dim3(4,1,128),256,0,stream>>>(adj, 0, feats, 68, 136,0, 2.f, -1.f);
    k_gw<204,68,128,8,64,0><<<dim3(1024,1),256,0,stream>>>(feats, wr_eg, egb, 128, henc, zh, rb);
    k_pack<64,1,68><<<(encPack+255)/256,256,0,stream>>>(zh, e0a, e0b, 6144, nullptr, 0, feats, encPack);
    k_mm<64,1,68><<<dim3(4,1,128),256,0,stream>>>(adj, 0, feats, 0,  68, 0, 1.f,  0.f);
    k_mm<64,1,68><<<dim3(4,1,128),256,0,stream>>>(adj, 0, feats, 68, 136,0, 2.f, -1.f);
    k_gw<204,68,64,4,64,1><<<dim3(1024,1),256,0,stream>>>(feats, wr_eu, eub, 64, henc, henc, rb);
  }

  // ---------------- memory query / latent / support ----------------
  k_query<<<16384,256,0,stream>>>(henc, Wq, Mem, haug, it, ih);
  k_latent<<<128,256,0,stream>>>(it, ih, Mem, lW, lb, outl);
  k_emb<<<2048,256,0,stream>>>(haug, hW, hb, emb);
  k_support<<<32768,256,0,stream>>>(emb, sup);

  // ---------------- decoder (BB=64) ----------------
  const int decPack = 64*512*132;
  for (int t = 0; t < 12; t++){
    const float* e1 = y_cov + t*512;
    k_pack<128,2,132><<<(decPack+255)/256,256,0,stream>>>(haug, go, go, 512, e1, 6144, feats, decPack);
    k_mm<128,2,132><<<dim3(4,2,64),256,0,stream>>>(sup, 262144, feats, 0,   132, 0, 1.f,  0.f);
    k_mm<128,2,132><<<dim3(4,2,64),256,0,stream>>>(sup, 262144, feats, 132, 264, 0, 2.f, -1.f);
    k_gw<396,66,128,8,128,0><<<dim3(512,2),256,0,stream>>>(feats, wr_dg, dgb, 256, haug, zh, rb);
    k_pack<128,2,132><<<(decPack+255)/256,256,0,stream>>>(zh, go, go, 512, e1, 6144, feats, decPack);
    k_mm<128,2,132><<<dim3(4,2,64),256,0,stream>>>(sup, 262144, feats, 0,   132, 0, 1.f,  0.f);
    k_mm<128,2,132><<<dim3(4,2,64),256,0,stream>>>(sup, 262144, feats, 132, 264, 0, 2.f, -1.f);
    k_gw<396,66,128,8,128,1><<<dim3(512,1),256,0,stream>>>(feats, wr_du, dub, 128, haug, haug, rb);
    k_proj<<<8192,256,0,stream>>>(haug, pW, pb, go, out, t);
  }
}

// Round 3
// 8093.649 us; speedup vs baseline: 1.6549x; 1.6549x over previous
//
#include <hip/hip_runtime.h>
#include <hip/hip_bf16.h>

// MDGCRN hybrid: fp32 encoder (argmax-exact path) + bf16-MFMA decoder.
// B=64,T=12,N=512,HORIZON=12,RNN=64,MEM=20x64,EMB=10,CHEB_K=3,DEC_DIM=128
// Encoder fp32: feats (128*512 rows)x204, henc row-major (rows)x64.
// Decoder bf16: fR[row][448] row-major K-contig, fC[bb][seg(144)][c][512] col-major.

typedef __attribute__((ext_vector_type(8))) short s8v;
typedef __attribute__((ext_vector_type(4))) float f4v;
typedef __attribute__((ext_vector_type(4))) unsigned short u4v;

__device__ __forceinline__ float b2f(unsigned short u){
  union{unsigned int i; float f;} v; v.i = ((unsigned int)u)<<16; return v.f;
}
__device__ __forceinline__ unsigned short f2b(float f){
  union{float f; unsigned int i;} v; v.f = f;
  unsigned int r = v.i + 0x7fff + ((v.i >> 16) & 1);   // RNE (finite inputs only)
  return (unsigned short)(r >> 16);
}

__global__ void k_zero16(uint4* p, int n){
  int i = blockIdx.x*256 + threadIdx.x;
  if (i < n) p[i] = make_uint4(0,0,0,0);
}

// ======================= fp32 ENCODER (R1 verbatim) =======================

__global__ void k_reorderF(const float* __restrict__ W, float* __restrict__ Wr,
                           int HC, int NEX, int SEGW, int J){
  int idx = blockIdx.x*256 + threadIdx.x;
  int K = 3*SEGW;
  if (idx >= K*J) return;
  int k = idx / J, j = idx - k*J;
  int seg = k / SEGW, c = k - seg*SEGW;
  int CIN = HC + NEX;
  float v = 0.f;
  if (c < HC)       v = W[(size_t)(seg*CIN + NEX + c)*J + j];
  else if (c < CIN) v = W[(size_t)(seg*CIN + (c-HC))*J + j];
  Wr[(size_t)k*J + j] = v;
}

template<int HC,int NEX,int SEGW>
__global__ void k_packF(const float* __restrict__ hsrc,
                        const float* __restrict__ e0a, const float* __restrict__ e0b, int e0bbs,
                        float* __restrict__ feats, int total){
  const int FS = 3*SEGW;
  int idx = blockIdx.x*256 + threadIdx.x;
  if (idx >= total) return;
  int row = idx / SEGW, c = idx - row*SEGW;
  float v;
  if (c < HC) v = hsrc[(size_t)row*HC + c];
  else if (c < HC+NEX){
    int bb = row >> 9, m = row & 511;
    v = (bb < 64) ? e0a[(size_t)bb*e0bbs + m] : e0b[(size_t)(bb-64)*e0bbs + m];
  } else {
    v = 0.f;
    feats[(size_t)row*FS + SEGW   + c] = 0.f;
    feats[(size_t)row*FS + 2*SEGW + c] = 0.f;
  }
  feats[(size_t)row*FS + c] = v;
}

template<int HC,int NEX,int SEGW>
__global__ __launch_bounds__(256) void k_mmF(
    const float* __restrict__ M,
    float* __restrict__ feats, int xseg, int oseg, int yseg,
    float alpha, float beta){
  const int FS = 3*SEGW;
  int t = threadIdx.x;
  int bb = blockIdx.z;
  int n0 = blockIdx.x * 128;
  const float* Mb = M;
  const float* Xb = feats + (size_t)bb*512*FS + xseg;
  const float* Yb = feats + (size_t)bb*512*FS + yseg;
  float*       Ob = feats + (size_t)bb*512*FS + oseg;
  __shared__ float Ms[32][132];
  __shared__ float Bs[32][68];
  int tr = t & 15, tc = t >> 4;
  float acc[8][4];
  #pragma unroll
  for (int i=0;i<8;i++){
    #pragma unroll
    for (int c=0;c<4;c++) acc[i][c] = 0.f;
  }
  float acce[NEX];
  #pragma unroll
  for (int j=0;j<NEX;j++) acce[j]=0.f;
  const bool doe = (t < 128);
  for (int k0=0;k0<512;k0+=32){
    #pragma unroll
    for (int i=0;i<4;i++){
      int s = t + i*256;
      int r = s >> 3, kq = s & 7;
      const float4 v = *(const float4*)(Mb + (size_t)(n0+r)*512 + k0 + kq*4);
      Ms[kq*4+0][r]=v.x; Ms[kq*4+1][r]=v.y; Ms[kq*4+2][r]=v.z; Ms[kq*4+3][r]=v.w;
    }
    #pragma unroll
    for (int i=0;i<2;i++){
      int s = t + i*256;
      int k = s >> 4, cq = s & 15;
      const float4 v = *(const float4*)(Xb + (size_t)(k0+k)*FS + cq*4);
      *(float4*)&Bs[k][cq*4] = v;
    }
    if (t < 32*NEX){
      int k = t & 31, j = t >> 5;
      Bs[k][64+j] = Xb[(size_t)(k0+k)*FS + HC + j];
    }
    __syncthreads();
    #pragma unroll 8
    for (int k=0;k<32;k++){
      float4 a0 = *(const float4*)&Ms[k][tr*8];
      float4 a1 = *(const float4*)&Ms[k][tr*8+4];
      float4 b  = *(const float4*)&Bs[k][tc*4];
      float av[8] = {a0.x,a0.y,a0.z,a0.w,a1.x,a1.y,a1.z,a1.w};
      float bv[4] = {b.x,b.y,b.z,b.w};
      #pragma unroll
      for (int i=0;i<8;i++){
        #pragma unroll
        for (int c=0;c<4;c++) acc[i][c] += av[i]*bv[c];
      }
    }
    if (doe){
      #pragma unroll 8
      for (int k=0;k<32;k++){
        float av = Ms[k][t];
        #pragma unroll
        for (int j=0;j<NEX;j++) acce[j] += av * Bs[k][64+j];
      }
    }
    __syncthreads();
  }
  #pragma unroll
  for (int i=0;i<8;i++){
    int rr = n0 + tr*8 + i;
    float4 o;
    o.x = alpha*acc[i][0]; o.y = alpha*acc[i][1]; o.z = alpha*acc[i][2]; o.w = alpha*acc[i][3];
    if (beta != 0.f){
      const float4 y = *(const float4*)(Yb + (size_t)rr*FS + tc*4);
      o.x += beta*y.x; o.y += beta*y.y; o.z += beta*y.z; o.w += beta*y.w;
    }
    *(float4*)(Ob + (size_t)rr*FS + tc*4) = o;
  }
  if (doe){
    #pragma unroll
    for (int j=0;j<NEX;j++){
      float ov = alpha*acce[j];
      if (beta != 0.f) ov += beta * Yb[(size_t)(n0+t)*FS + HC + j];
      Ob[(size_t)(n0+t)*FS + HC + j] = ov;
    }
  }
}

template<int K,int KC,int JT,int TN,int Hdim,int MODE>
__global__ __launch_bounds__(256) void k_gwF(
    const float* __restrict__ feats, const float* __restrict__ Wr,
    const float* __restrict__ bias, int Jtot,
    const float* __restrict__ hbuf, float* __restrict__ outp, float* __restrict__ rbuf){
  __shared__ float As[KC][68];
  __shared__ float Ws[KC][JT];
  int t = threadIdx.x;
  int row0 = blockIdx.x*64, j0 = blockIdx.y*JT;
  int tr = t & 15, tc = t >> 4;
  float acc[4][TN];
  #pragma unroll
  for (int i=0;i<4;i++){
    #pragma unroll
    for (int j=0;j<TN;j++) acc[i][j]=0.f;
  }
  for (int kc0=0; kc0<K; kc0+=KC){
    for (int s=t; s<64*KC; s+=256){
      int r = s / KC, k = s - r*KC;
      As[k][r] = feats[(size_t)(row0+r)*K + kc0 + k];
    }
    for (int s=t; s<KC*JT; s+=256){
      int k = s / JT, j = s - k*JT;
      Ws[k][j] = Wr[(size_t)(kc0+k)*Jtot + j0 + j];
    }
    __syncthreads();
    #pragma unroll 4
    for (int k=0;k<KC;k++){
      float4 a = *(const float4*)&As[k][tr*4];
      float av[4] = {a.x,a.y,a.z,a.w};
      #pragma unroll
      for (int jj=0;jj<TN;jj+=4){
        float4 w = *(const float4*)&Ws[k][tc*TN+jj];
        float wv[4] = {w.x,w.y,w.z,w.w};
        #pragma unroll
        for (int i=0;i<4;i++){
          #pragma unroll
          for (int c=0;c<4;c++) acc[i][jj+c] += av[i]*wv[c];
        }
      }
    }
    __syncthreads();
  }
  #pragma unroll
  for (int i=0;i<4;i++){
    int row = row0 + tr*4 + i;
    #pragma unroll
    for (int jj=0;jj<TN;jj++){
      int j = j0 + tc*TN + jj;
      float xv = acc[i][jj] + bias[j];
      if (MODE == 0){
        float s = 1.f/(1.f + __expf(-xv));
        if (j < Hdim) outp[(size_t)row*Hdim + j] = s * hbuf[(size_t)row*Hdim + j];
        else          rbuf[(size_t)row*Hdim + (j-Hdim)] = s;
      } else {
        float hc = 1.f - 2.f/(__expf(2.f*xv) + 1.f);
        float rr = rbuf[(size_t)row*Hdim + j];
        outp[(size_t)row*Hdim + j] = rr*hbuf[(size_t)row*Hdim + j] + (1.f-rr)*hc;
      }
    }
  }
}

// ======================= bf16 DECODER (R2 verbatim) =======================

__global__ void k_reorderB(const float* __restrict__ W, unsigned short* __restrict__ Wr,
                           int HC, int NEX, int C, int KP, int J){
  int idx = blockIdx.x*256 + threadIdx.x;
  if (idx >= J*KP) return;
  int j = idx / KP, kp = idx - j*KP;
  float v = 0.f;
  if (kp < 3*C){
    int seg = kp / C, c = kp - seg*C;
    int CIN = HC + NEX;
    if (c < HC)       v = W[(size_t)(seg*CIN + NEX + c)*J + j];
    else if (c < CIN) v = W[(size_t)(seg*CIN + (c-HC))*J + j];
  }
  Wr[(size_t)j*KP + kp] = f2b(v);
}

template<int C16, bool BETA>
__global__ __launch_bounds__(256) void k_mmB(
    const unsigned short* __restrict__ M, long long mstride,
    unsigned short* fC, int C3, int xseg, int oseg,
    unsigned short* fR, int KP, float alpha)
{
  constexpr int C = C16*16;
  constexpr int BIT = (C*4 + 255)/256;
  __shared__ unsigned short Bs[C*40];
  const int t = threadIdx.x;
  const int w = t >> 6, L = t & 63, lm = L & 15, q = L >> 4;
  const int bb = blockIdx.z;
  const int n0 = blockIdx.x * 128;
  const unsigned short* Mb = M + (size_t)bb * mstride;
  unsigned short* fCb = fC + (size_t)bb * C3 * 512;
  const unsigned short* Xb = fCb + (size_t)xseg * C * 512;
  const unsigned short* Yb = fCb;
  unsigned short* Ob = fCb + (size_t)oseg * C * 512;
  const int rw = n0 + w*32;

  f4v acc[2][C16];
  #pragma unroll
  for (int i=0;i<2;i++)
    #pragma unroll
    for (int j=0;j<C16;j++)
      #pragma unroll
      for (int r=0;r<4;r++) acc[i][j][r] = 0.f;

  s8v breg[BIT];
  const size_t ar0 = (size_t)(rw + lm)*512 + q*8;
  const size_t ar1 = (size_t)(rw + 16 + lm)*512 + q*8;

  #pragma unroll
  for (int i=0;i<BIT;i++){
    int s = t + i*256;
    if (s < C*4) breg[i] = *(const s8v*)(Xb + (size_t)(s>>2)*512 + (s&3)*8);
  }
  s8v a0 = *(const s8v*)(Mb + ar0);
  s8v a1 = *(const s8v*)(Mb + ar1);

  for (int ks=0; ks<16; ks++){
    #pragma unroll
    for (int i=0;i<BIT;i++){
      int s = t + i*256;
      if (s < C*4) *(s8v*)&Bs[(s>>2)*40 + (s&3)*8] = breg[i];
    }
    __syncthreads();
    const int kn = (ks < 15) ? (ks+1)*32 : 0;
    #pragma unroll
    for (int i=0;i<BIT;i++){
      int s = t + i*256;
      if (s < C*4) breg[i] = *(const s8v*)(Xb + (size_t)(s>>2)*512 + kn + (s&3)*8);
    }
    s8v a0n = *(const s8v*)(Mb + ar0 + kn);
    s8v a1n = *(const s8v*)(Mb + ar1 + kn);
    #pragma unroll
    for (int ct=0; ct<C16; ct++){
      s8v b = *(const s8v*)&Bs[(ct*16+lm)*40 + q*8];
      acc[0][ct] = __builtin_amdgcn_mfma_f32_16x16x32_bf16(a0, b, acc[0][ct], 0,0,0);
      acc[1][ct] = __builtin_amdgcn_mfma_f32_16x16x32_bf16(a1, b, acc[1][ct], 0,0,0);
    }
    __syncthreads();
    a0 = a0n; a1 = a1n;
  }
  #pragma unroll
  for (int rt=0; rt<2; rt++){
    const int m0 = rw + rt*16 + q*4;
    #pragma unroll
    for (int ct=0; ct<C16; ct++){
      const int c = ct*16 + lm;
      u4v o;
      if (BETA){
        u4v y = *(const u4v*)(Yb + (size_t)c*512 + m0);
        #pragma unroll
        for (int r=0;r<4;r++) o[r] = f2b(alpha*acc[rt][ct][r] - b2f(y[r]));
      } else {
        #pragma unroll
        for (int r=0;r<4;r++) o[r] = f2b(acc[rt][ct][r]);
      }
      *(u4v*)(Ob + (size_t)c*512 + m0) = o;
      const size_t rbase = (size_t)(bb*512 + m0)*KP + oseg*C + c;
      #pragma unroll
      for (int r=0;r<4;r++) fR[rbase + (size_t)r*KP] = o[r];
    }
  }
}

template<int KSTEPS, int JT16, int MODE, int HC>
__global__ __launch_bounds__(256) void k_gwB(
    unsigned short* fR, int KP,
    const unsigned short* __restrict__ Wr, const float* __restrict__ bias,
    unsigned short* fC, int C3,
    float* hC, float* rbuf)
{
  constexpr int JT = JT16*16;
  constexpr int BIT = JT*4/256;
  __shared__ unsigned short Bs[JT*40];
  const int t = threadIdx.x;
  const int w = t >> 6, L = t & 63, lm = L & 15, q = L >> 4;
  const int row0 = blockIdx.x * 128;
  const int j0 = blockIdx.y * JT;
  const int rw = row0 + w*32;

  f4v acc[2][JT16];
  #pragma unroll
  for (int i=0;i<2;i++)
    #pragma unroll
    for (int j=0;j<JT16;j++)
      #pragma unroll
      for (int r=0;r<4;r++) acc[i][j][r] = 0.f;

  s8v breg[BIT];
  const unsigned short* Wb = Wr + (size_t)j0*KP;
  const size_t ar0 = (size_t)(rw + lm)*KP + q*8;
  const size_t ar1 = (size_t)(rw + 16 + lm)*KP + q*8;

  #pragma unroll
  for (int i=0;i<BIT;i++){
    int s = t + i*256;
    breg[i] = *(const s8v*)(Wb + (size_t)(s>>2)*KP + (s&3)*8);
  }
  s8v a0 = *(const s8v*)(fR + ar0);
  s8v a1 = *(const s8v*)(fR + ar1);

  for (int ks=0; ks<KSTEPS; ks++){
    #pragma unroll
    for (int i=0;i<BIT;i++){
      int s = t + i*256;
      *(s8v*)&Bs[(s>>2)*40 + (s&3)*8] = breg[i];
    }
    __syncthreads();
    const int kn = (ks < KSTEPS-1) ? (ks+1)*32 : 0;
    #pragma unroll
    for (int i=0;i<BIT;i++){
      int s = t + i*256;
      breg[i] = *(const s8v*)(Wb + (size_t)(s>>2)*KP + kn + (s&3)*8);
    }
    s8v a0n = *(const s8v*)(fR + ar0 + kn);
    s8v a1n = *(const s8v*)(fR + ar1 + kn);
    #pragma unroll
    for (int ct=0; ct<JT16; ct++){
      s8v b = *(const s8v*)&Bs[(ct*16+lm)*40 + q*8];
      acc[0][ct] = __builtin_amdgcn_mfma_f32_16x16x32_bf16(a0, b, acc[0][ct], 0,0,0);
      acc[1][ct] = __builtin_amdgcn_mfma_f32_16x16x32_bf16(a1, b, acc[1][ct], 0,0,0);
    }
    __syncthreads();
    a0 = a0n; a1 = a1n;
  }
  #pragma unroll
  for (int rt=0; rt<2; rt++){
    const int m0 = rw + rt*16 + q*4;
    const int bb = m0 >> 9, n = m0 & 511;
    #pragma unroll
    for (int ct=0; ct<JT16; ct++){
      const int j = j0 + ct*16 + lm;
      const float bj = bias[j];
      if (MODE == 0){
        if (j < HC){
          f4v h4 = *(const f4v*)(hC + ((size_t)bb*HC + j)*512 + n);
          u4v o;
          #pragma unroll
          for (int r=0;r<4;r++){
            float s = 1.f/(1.f + __expf(-(acc[rt][ct][r] + bj)));
            float zh = s * h4[r];
            o[r] = f2b(zh);
            fR[(size_t)(m0+r)*KP + j] = o[r];
          }
          *(u4v*)(fC + ((size_t)bb*C3 + j)*512 + n) = o;
        } else {
          f4v rv;
          #pragma unroll
          for (int r=0;r<4;r++) rv[r] = 1.f/(1.f + __expf(-(acc[rt][ct][r] + bj)));
          *(f4v*)(rbuf + ((size_t)bb*HC + (j-HC))*512 + n) = rv;
        }
      } else {
        f4v h4 = *(const f4v*)(hC + ((size_t)bb*HC + j)*512 + n);
        f4v r4 = *(const f4v*)(rbuf + ((size_t)bb*HC + j)*512 + n);
        u4v o; f4v hn;
        #pragma unroll
        for (int r=0;r<4;r++){
          float e = __expf(2.f*(acc[rt][ct][r] + bj));
          float hc_ = 1.f - 2.f/(e + 1.f);
          hn[r] = r4[r]*h4[r] + (1.f - r4[r])*hc_;
          o[r] = f2b(hn[r]);
          fR[(size_t)(m0+r)*KP + j] = o[r];
        }
        *(f4v*)(hC + ((size_t)bb*HC + j)*512 + n) = hn;
        *(u4v*)(fC + ((size_t)bb*C3 + j)*512 + n) = o;
      }
    }
  }
}

// ======================= glue kernels =======================

__global__ void k_extras_dec(const float* __restrict__ yc,
    unsigned short* fR, unsigned short* fC, int tstep){
  int rr = blockIdx.x*256 + threadIdx.x;   // 32768
  int bb = rr >> 9, n = rr & 511;
  unsigned short u = f2b(yc[((size_t)bb*12 + tstep)*512 + n]);
  fR[(size_t)rr*448 + 129] = u;
  fC[((size_t)bb*432 + 129)*512 + n] = u;
}
__global__ void k_fix_go(unsigned short* fR, unsigned short* fC){
  int rr = blockIdx.x*256 + threadIdx.x;   // 32768
  int bb = rr >> 9, n = rr & 511;
  fR[(size_t)rr*448 + 128] = 0;
  fC[((size_t)bb*432 + 128)*512 + n] = 0;
}

__global__ __launch_bounds__(256) void k_query(const float* __restrict__ hR,
      const float* __restrict__ Wq, const float* __restrict__ Mem,
      float* __restrict__ hCd, unsigned short* fR, unsigned short* fC,
      int* __restrict__ it, int* __restrict__ ih){
  int sub = threadIdx.x >> 6, lane = threadIdx.x & 63;
  int row = blockIdx.x*4 + sub;          // 0..65535
  __shared__ float sh[4][64], sq[4][64], ss[4][20];
  float hv = hR[(size_t)row*64 + lane];
  sh[sub][lane] = hv;
  __syncthreads();
  float qv = 0.f;
  for (int c=0;c<64;c++) qv += sh[sub][c]*Wq[c*64 + lane];
  sq[sub][lane] = qv;
  __syncthreads();
  if (lane < 20){
    float s = 0.f;
    for (int j=0;j<64;j++) s += sq[sub][j]*Mem[lane*64 + j];
    ss[sub][lane] = s;
  }
  __syncthreads();
  float mx = -1e30f; int am = 0;
  for (int m=0;m<20;m++){ float s = ss[sub][m]; if (s > mx){ mx = s; am = m; } }
  float sum = 0.f;
  for (int m=0;m<20;m++) sum += __expf(ss[sub][m]-mx);
  float inv = 1.f/sum;
  float v = 0.f;
  for (int m=0;m<20;m++) v += __expf(ss[sub][m]-mx)*inv*Mem[m*64 + lane];
  int bb = row >> 9, n = row & 511;
  if (bb < 64){
    hCd[((size_t)bb*128 + lane)*512 + n] = hv;
    hCd[((size_t)bb*128 + 64 + lane)*512 + n] = v;
    fR[(size_t)row*448 + lane] = f2b(hv);
    fR[(size_t)row*448 + 64 + lane] = f2b(v);
    fC[((size_t)bb*432 + lane)*512 + n] = f2b(hv);
    fC[((size_t)bb*432 + 64 + lane)*512 + n] = f2b(v);
    if (lane==0) it[row] = am;
  } else {
    if (lane==0) ih[row - 32768] = am;
  }
}

__global__ void k_latent(const int* __restrict__ it, const int* __restrict__ ih,
                         const float* __restrict__ Mem,
                         const float* __restrict__ lW, const float* __restrict__ lb,
                         float* __restrict__ outl){
  int row = blockIdx.x*256 + threadIdx.x;  // 32768
  int i1 = it[row], i2 = ih[row];
  float a = lb[0];
  for (int c=0;c<64;c++) a += (Mem[i1*64+c]-Mem[i2*64+c])*lW[c];
  outl[row] = 1.f/(1.f + __expf(-a));
}

__global__ __launch_bounds__(256) void k_emb(const float* __restrict__ hCd,
    const float* __restrict__ hW, const float* __restrict__ hb, float* __restrict__ emb){
  __shared__ float sW[1280];
  int t = threadIdx.x;
  for (int s=t; s<1280; s+=256) sW[s] = hW[s];
  __syncthreads();
  int rr = blockIdx.x*256 + t;   // 32768
  int bb = rr >> 9, n = rr & 511;
  float a[10];
  #pragma unroll
  for (int e=0;e<10;e++) a[e] = hb[e];
  for (int c=0;c<128;c++){
    float v = hCd[((size_t)bb*128 + c)*512 + n];
    #pragma unroll
    for (int e=0;e<10;e++) a[e] += v*sW[c*10+e];
  }
  #pragma unroll
  for (int e=0;e<10;e++) emb[(size_t)rr*10 + e] = a[e];
}

__global__ __launch_bounds__(256) void k_support(const float* __restrict__ emb,
                                                 unsigned short* __restrict__ sup){
  int b = blockIdx.x >> 9;
  int n = blockIdx.x & 511;
  int t = threadIdx.x;
  __shared__ float se[5120];
  __shared__ float red[8];
  for (int s = t; s < 5120; s += 256) se[s] = emb[(size_t)b*5120 + s];
  __syncthreads();
  float en[10];
  #pragma unroll
  for (int i=0;i<10;i++) en[i] = se[n*10+i];
  float s0=0.f, s1=0.f;
  #pragma unroll
  for (int i=0;i<10;i++){ s0 += en[i]*se[t*10+i]; s1 += en[i]*se[(t+256)*10+i]; }
  s0 = fmaxf(s0, 0.f); s1 = fmaxf(s1, 0.f);
  float mx = fmaxf(s0, s1);
  for (int o=32;o>0;o>>=1) mx = fmaxf(mx, __shfl_down(mx, o));
  if ((t&63)==0) red[t>>6] = mx;
  __syncthreads();
  mx = fmaxf(fmaxf(red[0],red[1]), fmaxf(red[2],red[3]));
  float e0 = __expf(s0-mx), e1 = __expf(s1-mx);
  float sm = e0 + e1;
  for (int o=32;o>0;o>>=1) sm += __shfl_down(sm, o);
  if ((t&63)==0) red[4+(t>>6)] = sm;
  __syncthreads();
  sm = red[4]+red[5]+red[6]+red[7];
  float inv = 1.f/sm;
  size_t base = ((size_t)b*512 + n)*512;
  sup[base + t]       = f2b(e0*inv);
  sup[base + t + 256] = f2b(e1*inv);
}

__global__ __launch_bounds__(256) void k_proj(const float* __restrict__ hCd,
    const float* __restrict__ pW, const float* __restrict__ pb,
    unsigned short* fR, unsigned short* fC, float* __restrict__ out, int tstep){
  __shared__ float sW[128];
  int t = threadIdx.x;
  if (t < 128) sW[t] = pW[t];
  __syncthreads();
  int rr = blockIdx.x*256 + t;   // 32768
  int bb = rr >> 9, n = rr & 511;
  float a = pb[0];
  for (int c=0;c<128;c++) a += hCd[((size_t)bb*128 + c)*512 + n]*sW[c];
  out[((size_t)bb*12 + tstep)*512 + n] = a;
  unsigned short u = f2b(a);
  fR[(size_t)rr*448 + 128] = u;
  fC[((size_t)bb*432 + 128)*512 + n] = u;
}

extern "C" void kernel_launch(void* const* d_in, const int* in_sizes, int n_in,
                              void* d_out, int out_size, void* d_ws, size_t ws_size,
                              hipStream_t stream) {
  const float* x     = (const float*)d_in[0];
  const float* x_his = (const float*)d_in[2];
  const float* y_cov = (const float*)d_in[3];
  const float* adj   = (const float*)d_in[4];
  const float* egW   = (const float*)d_in[5];
  const float* egb   = (const float*)d_in[6];
  const float* euW   = (const float*)d_in[7];
  const float* eub   = (const float*)d_in[8];
  const float* dgW   = (const float*)d_in[9];
  const float* dgb   = (const float*)d_in[10];
  const float* duW   = (const float*)d_in[11];
  const float* dub   = (const float*)d_in[12];
  const float* Mem   = (const float*)d_in[13];
  const float* Wq    = (const float*)d_in[14];
  const float* hW    = (const float*)d_in[15];
  const float* hb    = (const float*)d_in[16];
  const float* lW    = (const float*)d_in[17];
  const float* lb    = (const float*)d_in[18];
  const float* pW    = (const float*)d_in[19];
  const float* pb    = (const float*)d_in[20];
  float* out  = (float*)d_out;           // (64,12,512,1)
  float* outl = out + 393216;            // (64,512)

  char* base = (char*)d_ws;
  size_t off = 0;
  auto alloc = [&](size_t bytes)->char*{
    char* p = base + off; off = (off + bytes + 255) & ~(size_t)255; return p;
  };
  float* featsF = (float*)alloc(53477376);       // 128*512*204 fp32 (encoder)
  //   decoder-phase aliases inside featsF (encoder feats dead by then):
  unsigned short* sup = (unsigned short*)featsF;            // 64*512*512 bf16 = 33.5MB
  float* emb = featsF + 8650752;                            // 32768*10 fp32
  int*   it  = (int*)(featsF + 9961472);                    // 32768
  int*   ih  = it + 32768;                                  // 32768
  float* henc = (float*)alloc(16777216);         // (128*512)x64 fp32, row-major
  float* zhF  = (float*)alloc(16777216);         // enc z*h (row-major); aliased as hCd in decoder
  float* hCd  = zhF;                             // (64,128,512) fp32 col-major decoder state
  float* rbF  = (float*)alloc(16777216);         // enc r (row-major) / dec r (col-major)
  unsigned short* fR = (unsigned short*)alloc(29360128);  // 32768 x 448 bf16
  unsigned short* fC = (unsigned short*)alloc(28311552);  // 64 x 432 x 512 bf16
  float* wr_egF = (float*)alloc(104448);         // 204x128 fp32
  float* wr_euF = (float*)alloc(52224);          // 204x64 fp32
  unsigned short* wr_dg = (unsigned short*)alloc(229376); // 256x448 bf16
  unsigned short* wr_du = (unsigned short*)alloc(114688); // 128x448 bf16
  if (ws_size < off) return;

  // init (ws is re-poisoned every call)
  k_zero16<<<4096,256,0,stream>>>((uint4*)henc, 1048576);
  k_zero16<<<7168,256,0,stream>>>((uint4*)fR, 1835008);
  k_zero16<<<6912,256,0,stream>>>((uint4*)fC, 1769472);
  k_reorderF<<<102,256,0,stream>>>(egW, wr_egF, 64,1,68,128);
  k_reorderF<<< 51,256,0,stream>>>(euW, wr_euF, 64,1,68,64);
  k_reorderB<<<448,256,0,stream>>>(dgW, wr_dg, 128,2,144,448,256);
  k_reorderB<<<224,256,0,stream>>>(duW, wr_du, 128,2,144,448,128);

  // ---------------- fp32 encoders: x | x_his stacked, BB=128 ----------------
  const int encPack = 128*512*68;
  for (int t = 0; t < 12; t++){
    const float* e0a = x + t*512;
    const float* e0b = x_his + t*512;
    k_packF<64,1,68><<<(encPack+255)/256,256,0,stream>>>(henc, e0a, e0b, 6144, featsF, encPack);
    k_mmF<64,1,68><<<dim3(4,1,128),256,0,stream>>>(adj, featsF, 0,  68, 0, 1.f,  0.f);
    k_mmF<64,1,68><<<dim3(4,1,128),256,0,stream>>>(adj, featsF, 68, 136,0, 2.f, -1.f);
    k_gwF<204,68,128,8,64,0><<<dim3(1024,1),256,0,stream>>>(featsF, wr_egF, egb, 128, henc, zhF, rbF);
    k_packF<64,1,68><<<(encPack+255)/256,256,0,stream>>>(zhF, e0a, e0b, 6144, featsF, encPack);
    k_mmF<64,1,68><<<dim3(4,1,128),256,0,stream>>>(adj, featsF, 0,  68, 0, 1.f,  0.f);
    k_mmF<64,1,68><<<dim3(4,1,128),256,0,stream>>>(adj, featsF, 68, 136,0, 2.f, -1.f);
    k_gwF<204,68,64,4,64,1><<<dim3(1024,1),256,0,stream>>>(featsF, wr_euF, eub, 64, henc, henc, rbF);
  }

  // ---------------- memory query / latent / support (fp32 scores) ----------------
  k_query<<<16384,256,0,stream>>>(henc, Wq, Mem, hCd, fR, fC, it, ih);
  k_latent<<<128,256,0,stream>>>(it, ih, Mem, lW, lb, outl);
  k_emb<<<128,256,0,stream>>>(hCd, hW, hb, emb);
  k_support<<<32768,256,0,stream>>>(emb, sup);
  k_fix_go<<<128,256,0,stream>>>(fR, fC);

  // ---------------- bf16 decoder, BB=64 ----------------
  for (int t = 0; t < 12; t++){
    k_extras_dec<<<128,256,0,stream>>>(y_cov, fR, fC, t);
    k_mmB<9,false><<<dim3(4,1,64),256,0,stream>>>(sup, 262144, fC, 432, 0, 1, fR, 448, 1.f);
    k_mmB<9,true ><<<dim3(4,1,64),256,0,stream>>>(sup, 262144, fC, 432, 1, 2, fR, 448, 2.f);
    k_gwB<14,16,0,128><<<dim3(256,1),256,0,stream>>>(fR, 448, wr_dg, dgb, fC, 432, hCd, rbF);
    k_mmB<9,false><<<dim3(4,1,64),256,0,stream>>>(sup, 262144, fC, 432, 0, 1, fR, 448, 1.f);
    k_mmB<9,true ><<<dim3(4,1,64),256,0,stream>>>(sup, 262144, fC, 432, 1, 2, fR, 448, 2.f);
    k_gwB<14,8,1,128><<<dim3(256,1),256,0,stream>>>(fR, 448, wr_du, dub, fC, 432, hCd, rbF);
    k_proj<<<128,256,0,stream>>>(hCd, pW, pb, fR, fC, out, t);
  }
}

// Round 4
// 7173.284 us; speedup vs baseline: 1.8672x; 1.1283x over previous
//
#include <hip/hip_runtime.h>
#include <hip/hip_bf16.h>

// MDGCRN hybrid: fp32 encoder (argmax-exact path) + bf16-MFMA decoder.
// R4: encoder restructured — A2e=2A^2-I fused dual-conv (k_mm2F, pack folded in),
//     retiled feats@W (k_gwG/k_gwU). Decoder unchanged from R3.

typedef __attribute__((ext_vector_type(8))) short s8v;
typedef __attribute__((ext_vector_type(4))) float f4v;
typedef __attribute__((ext_vector_type(4))) unsigned short u4v;

__device__ __forceinline__ float b2f(unsigned short u){
  union{unsigned int i; float f;} v; v.i = ((unsigned int)u)<<16; return v.f;
}
__device__ __forceinline__ unsigned short f2b(float f){
  union{float f; unsigned int i;} v; v.f = f;
  unsigned int r = v.i + 0x7fff + ((v.i >> 16) & 1);   // RNE (finite inputs only)
  return (unsigned short)(r >> 16);
}

__global__ void k_zero16(uint4* p, int n){
  int i = blockIdx.x*256 + threadIdx.x;
  if (i < n) p[i] = make_uint4(0,0,0,0);
}

// ======================= fp32 ENCODER (R4 rewrite) =======================

__global__ void k_reorderF(const float* __restrict__ W, float* __restrict__ Wr,
                           int HC, int NEX, int SEGW, int J){
  int idx = blockIdx.x*256 + threadIdx.x;
  int K = 3*SEGW;
  if (idx >= K*J) return;
  int k = idx / J, j = idx - k*J;
  int seg = k / SEGW, c = k - seg*SEGW;
  int CIN = HC + NEX;
  float v = 0.f;
  if (c < HC)       v = W[(size_t)(seg*CIN + NEX + c)*J + j];
  else if (c < CIN) v = W[(size_t)(seg*CIN + (c-HC))*J + j];
  Wr[(size_t)k*J + j] = v;
}

// A2e = 2*A@A - I   (512x512)
__global__ __launch_bounds__(256) void k_a2e(const float* __restrict__ A,
                                             float* __restrict__ A2e){
  __shared__ __align__(16) float As[32][132];
  __shared__ __align__(16) float Bs[32][132];
  int t = threadIdx.x;
  int r0 = (blockIdx.x & 3) * 128;
  int c0 = (blockIdx.x >> 2) * 128;
  int tr = t & 15, tc = t >> 4;
  float acc[8][8];
  #pragma unroll
  for (int i=0;i<8;i++)
    #pragma unroll
    for (int j=0;j<8;j++) acc[i][j]=0.f;
  for (int k0=0;k0<512;k0+=32){
    #pragma unroll
    for (int i=0;i<4;i++){
      int s = t + i*256;
      int r = s >> 3, kq = s & 7;
      float4 v = *(const float4*)(A + (size_t)(r0+r)*512 + k0 + kq*4);
      As[kq*4+0][r]=v.x; As[kq*4+1][r]=v.y; As[kq*4+2][r]=v.z; As[kq*4+3][r]=v.w;
    }
    #pragma unroll
    for (int i=0;i<4;i++){
      int s = t + i*256;
      int k = s >> 5, cq = s & 31;
      float4 v = *(const float4*)(A + (size_t)(k0+k)*512 + c0 + cq*4);
      *(float4*)&Bs[k][cq*4] = v;
    }
    __syncthreads();
    #pragma unroll 8
    for (int k=0;k<32;k++){
      float a[8], b[8];
      *(float4*)&a[0] = *(const float4*)&As[k][tr*8];
      *(float4*)&a[4] = *(const float4*)&As[k][tr*8+4];
      *(float4*)&b[0] = *(const float4*)&Bs[k][tc*8];
      *(float4*)&b[4] = *(const float4*)&Bs[k][tc*8+4];
      #pragma unroll
      for (int i=0;i<8;i++)
        #pragma unroll
        for (int j=0;j<8;j++) acc[i][j] += a[i]*b[j];
    }
    __syncthreads();
  }
  #pragma unroll
  for (int i=0;i<8;i++){
    int r = r0 + tr*8 + i;
    #pragma unroll
    for (int j=0;j<8;j++){
      int c = c0 + tc*8 + j;
      A2e[(size_t)r*512 + c] = 2.f*acc[i][j] - (r==c ? 1.f : 0.f);
    }
  }
}

// Fused dual conv: seg0=[G0], G1=A@G0, G2=A2e@G0. G0=[hsrc|x] read directly.
// feats row layout (204): [h 0..63 | x 64 | pad | G1 68..132 | pad | G2 136..200 | pad]
// Block: 128 rows x 64 cols, 256 thr, TM=4 x TN=8 per matrix; x-col by all threads.
__global__ __launch_bounds__(256) void k_mm2F(
    const float* __restrict__ A, const float* __restrict__ A2e,
    const float* __restrict__ hsrc,             // [row][64] row-major
    const float* __restrict__ xa, const float* __restrict__ xb,  // (64,12,512) each
    int tstep, float* __restrict__ feats)
{
  __shared__ __align__(16) float As[32][132];
  __shared__ __align__(16) float A2s[32][132];
  __shared__ __align__(16) float Bs[32][68];
  const int t = threadIdx.x;
  const int bb = blockIdx.z;
  const int n0 = blockIdx.x * 128;
  const int tr = t & 31, tc = t >> 5;          // rows tr*4.., cols tc*8..
  const int xrow = t & 127, xmat = t >> 7;     // x-col: 128 rows x 2 mats
  const float* xp = (bb < 64) ? (xa + ((size_t)bb*12 + tstep)*512)
                              : (xb + ((size_t)(bb-64)*12 + tstep)*512);
  float acc1[4][8], acc2[4][8];
  #pragma unroll
  for (int i=0;i<4;i++)
    #pragma unroll
    for (int j=0;j<8;j++){ acc1[i][j]=0.f; acc2[i][j]=0.f; }
  float xacc = 0.f;

  for (int k0=0;k0<512;k0+=32){
    #pragma unroll
    for (int i=0;i<4;i++){
      int s = t + i*256;
      int r = s >> 3, kq = s & 7;
      float4 v = *(const float4*)(A + (size_t)(n0+r)*512 + k0 + kq*4);
      As[kq*4+0][r]=v.x; As[kq*4+1][r]=v.y; As[kq*4+2][r]=v.z; As[kq*4+3][r]=v.w;
      float4 w = *(const float4*)(A2e + (size_t)(n0+r)*512 + k0 + kq*4);
      A2s[kq*4+0][r]=w.x; A2s[kq*4+1][r]=w.y; A2s[kq*4+2][r]=w.z; A2s[kq*4+3][r]=w.w;
    }
    #pragma unroll
    for (int i=0;i<2;i++){
      int s = t + i*256;
      int k = s >> 4, cq = s & 15;
      float4 v = *(const float4*)(hsrc + (size_t)(bb*512 + k0 + k)*64 + cq*4);
      *(float4*)&Bs[k][cq*4] = v;
    }
    if (t < 32) Bs[t][64] = xp[k0 + t];
    __syncthreads();
    #pragma unroll 8
    for (int k=0;k<32;k++){
      float a1[4], a2[4], b[8];
      *(float4*)&a1[0] = *(const float4*)&As[k][tr*4];
      *(float4*)&a2[0] = *(const float4*)&A2s[k][tr*4];
      *(float4*)&b[0]  = *(const float4*)&Bs[k][tc*8];
      *(float4*)&b[4]  = *(const float4*)&Bs[k][tc*8+4];
      #pragma unroll
      for (int i=0;i<4;i++)
        #pragma unroll
        for (int j=0;j<8;j++){ acc1[i][j] += a1[i]*b[j]; acc2[i][j] += a2[i]*b[j]; }
      xacc += (xmat ? A2s[k][xrow] : As[k][xrow]) * Bs[k][64];
    }
    // seg0 writeback for this block's own rows (Bs holds G0 rows k0..k0+31)
    if ((k0 >> 7) == (int)blockIdx.x){
      for (int s=t; s<544; s+=256){          // 32 rows x 17 float4
        int k = s/17, q = s - k*17;
        float4 v;
        if (q < 16) v = *(const float4*)&Bs[k][q*4];
        else        v = make_float4(Bs[k][64], 0.f, 0.f, 0.f);
        *(float4*)(feats + (size_t)(bb*512 + k0 + k)*204 + q*4) = v;
      }
    }
    __syncthreads();
  }
  #pragma unroll
  for (int i=0;i<4;i++){
    int row = n0 + tr*4 + i;
    float* fr = feats + (size_t)(bb*512 + row)*204;
    float4 v;
    v.x=acc1[i][0]; v.y=acc1[i][1]; v.z=acc1[i][2]; v.w=acc1[i][3];
    *(float4*)(fr + 68 + tc*8) = v;
    v.x=acc1[i][4]; v.y=acc1[i][5]; v.z=acc1[i][6]; v.w=acc1[i][7];
    *(float4*)(fr + 68 + tc*8 + 4) = v;
    v.x=acc2[i][0]; v.y=acc2[i][1]; v.z=acc2[i][2]; v.w=acc2[i][3];
    *(float4*)(fr + 136 + tc*8) = v;
    v.x=acc2[i][4]; v.y=acc2[i][5]; v.z=acc2[i][6]; v.w=acc2[i][7];
    *(float4*)(fr + 136 + tc*8 + 4) = v;
  }
  feats[(size_t)(bb*512 + n0 + xrow)*204 + (xmat ? 136 : 68) + 64] = xacc;
}

// Gate: feats(204) @ Wr(204x128) -> sigmoid; j<64: zh=s*h, j>=64: rbuf=s
__global__ __launch_bounds__(256) void k_gwG(
    const float* __restrict__ feats, const float* __restrict__ Wr,
    const float* __restrict__ bias,
    const float* __restrict__ hbuf, float* __restrict__ zh, float* __restrict__ rbuf)
{
  __shared__ __align__(16) float As[17][132];
  __shared__ __align__(16) float Ws[17][132];
  const int t = threadIdx.x;
  const int row0 = blockIdx.x * 128;
  const int tr = t & 15, tc = t >> 4;      // rows tr*8, cols tc*8
  float acc[8][8];
  #pragma unroll
  for (int i=0;i<8;i++)
    #pragma unroll
    for (int j=0;j<8;j++) acc[i][j]=0.f;
  for (int kc=0; kc<204; kc+=17){
    for (int s=t; s<2176; s+=256){         // As: 128 rows x 17 k
      int r = s/17, k = s - r*17;
      As[k][r] = feats[(size_t)(row0+r)*204 + kc + k];
    }
    for (int s=t; s<2176; s+=256){         // Ws: 17 k x 128 j
      int k = s >> 7, j = s & 127;
      Ws[k][j] = Wr[(size_t)(kc+k)*128 + j];
    }
    __syncthreads();
    #pragma unroll
    for (int k=0;k<17;k++){
      float a[8], wv[8];
      *(float4*)&a[0]  = *(const float4*)&As[k][tr*8];
      *(float4*)&a[4]  = *(const float4*)&As[k][tr*8+4];
      *(float4*)&wv[0] = *(const float4*)&Ws[k][tc*8];
      *(float4*)&wv[4] = *(const float4*)&Ws[k][tc*8+4];
      #pragma unroll
      for (int i=0;i<8;i++)
        #pragma unroll
        for (int j=0;j<8;j++) acc[i][j] += a[i]*wv[j];
    }
    __syncthreads();
  }
  const int j0 = tc*8;
  float bj[8];
  #pragma unroll
  for (int j=0;j<8;j++) bj[j] = bias[j0+j];
  #pragma unroll
  for (int i=0;i<8;i++){
    int row = row0 + tr*8 + i;
    float s[8];
    #pragma unroll
    for (int j=0;j<8;j++) s[j] = 1.f/(1.f + __expf(-(acc[i][j] + bj[j])));
    if (j0 < 64){
      float4 h0 = *(const float4*)(hbuf + (size_t)row*64 + j0);
      float4 h1 = *(const float4*)(hbuf + (size_t)row*64 + j0 + 4);
      float4 o0, o1;
      o0.x=s[0]*h0.x; o0.y=s[1]*h0.y; o0.z=s[2]*h0.z; o0.w=s[3]*h0.w;
      o1.x=s[4]*h1.x; o1.y=s[5]*h1.y; o1.z=s[6]*h1.z; o1.w=s[7]*h1.w;
      *(float4*)(zh + (size_t)row*64 + j0)     = o0;
      *(float4*)(zh + (size_t)row*64 + j0 + 4) = o1;
    } else {
      float4 o0, o1;
      o0.x=s[0]; o0.y=s[1]; o0.z=s[2]; o0.w=s[3];
      o1.x=s[4]; o1.y=s[5]; o1.z=s[6]; o1.w=s[7];
      *(float4*)(rbuf + (size_t)row*64 + j0 - 64) = o0;
      *(float4*)(rbuf + (size_t)row*64 + j0 - 60) = o1;
    }
  }
}

// Update: feats(204) @ Wr(204x64) -> tanh; h = r*h + (1-r)*hc  (in-place on henc)
__global__ __launch_bounds__(256) void k_gwU(
    const float* __restrict__ feats, const float* __restrict__ Wr,
    const float* __restrict__ bias,
    float* __restrict__ henc, const float* __restrict__ rbuf)
{
  __shared__ __align__(16) float As[17][132];
  __shared__ __align__(16) float Ws[17][68];
  const int t = threadIdx.x;
  const int row0 = blockIdx.x * 128;
  const int tr = t & 15, tc = t >> 4;      // rows tr*8, cols tc*4
  float acc[8][4];
  #pragma unroll
  for (int i=0;i<8;i++)
    #pragma unroll
    for (int j=0;j<4;j++) acc[i][j]=0.f;
  for (int kc=0; kc<204; kc+=17){
    for (int s=t; s<2176; s+=256){
      int r = s/17, k = s - r*17;
      As[k][r] = feats[(size_t)(row0+r)*204 + kc + k];
    }
    for (int s=t; s<1088; s+=256){         // Ws: 17 x 64
      int k = s >> 6, j = s & 63;
      Ws[k][j] = Wr[(size_t)(kc+k)*64 + j];
    }
    __syncthreads();
    #pragma unroll
    for (int k=0;k<17;k++){
      float a[8], wv[4];
      *(float4*)&a[0]  = *(const float4*)&As[k][tr*8];
      *(float4*)&a[4]  = *(const float4*)&As[k][tr*8+4];
      *(float4*)&wv[0] = *(const float4*)&Ws[k][tc*4];
      #pragma unroll
      for (int i=0;i<8;i++)
        #pragma unroll
        for (int j=0;j<4;j++) acc[i][j] += a[i]*wv[j];
    }
    __syncthreads();
  }
  const int j0 = tc*4;
  float bj[4];
  #pragma unroll
  for (int j=0;j<4;j++) bj[j] = bias[j0+j];
  #pragma unroll
  for (int i=0;i<8;i++){
    int row = row0 + tr*8 + i;
    float4 h4 = *(const float4*)(henc + (size_t)row*64 + j0);
    float4 r4 = *(const float4*)(rbuf + (size_t)row*64 + j0);
    float hv[4] = {h4.x,h4.y,h4.z,h4.w};
    float rv[4] = {r4.x,r4.y,r4.z,r4.w};
    float4 o;
    float ov[4];
    #pragma unroll
    for (int j=0;j<4;j++){
      float hc = 1.f - 2.f/(__expf(2.f*(acc[i][j] + bj[j])) + 1.f);
      ov[j] = rv[j]*hv[j] + (1.f - rv[j])*hc;
    }
    o.x=ov[0]; o.y=ov[1]; o.z=ov[2]; o.w=ov[3];
    *(float4*)(henc + (size_t)row*64 + j0) = o;
  }
}

// ======================= bf16 DECODER (R3 verbatim) =======================

__global__ void k_reorderB(const float* __restrict__ W, unsigned short* __restrict__ Wr,
                           int HC, int NEX, int C, int KP, int J){
  int idx = blockIdx.x*256 + threadIdx.x;
  if (idx >= J*KP) return;
  int j = idx / KP, kp = idx - j*KP;
  float v = 0.f;
  if (kp < 3*C){
    int seg = kp / C, c = kp - seg*C;
    int CIN = HC + NEX;
    if (c < HC)       v = W[(size_t)(seg*CIN + NEX + c)*J + j];
    else if (c < CIN) v = W[(size_t)(seg*CIN + (c-HC))*J + j];
  }
  Wr[(size_t)j*KP + kp] = f2b(v);
}

template<int C16, bool BETA>
__global__ __launch_bounds__(256) void k_mmB(
    const unsigned short* __restrict__ M, long long mstride,
    unsigned short* fC, int C3, int xseg, int oseg,
    unsigned short* fR, int KP, float alpha)
{
  constexpr int C = C16*16;
  constexpr int BIT = (C*4 + 255)/256;
  __shared__ unsigned short Bs[C*40];
  const int t = threadIdx.x;
  const int w = t >> 6, L = t & 63, lm = L & 15, q = L >> 4;
  const int bb = blockIdx.z;
  const int n0 = blockIdx.x * 128;
  const unsigned short* Mb = M + (size_t)bb * mstride;
  unsigned short* fCb = fC + (size_t)bb * C3 * 512;
  const unsigned short* Xb = fCb + (size_t)xseg * C * 512;
  const unsigned short* Yb = fCb;
  unsigned short* Ob = fCb + (size_t)oseg * C * 512;
  const int rw = n0 + w*32;

  f4v acc[2][C16];
  #pragma unroll
  for (int i=0;i<2;i++)
    #pragma unroll
    for (int j=0;j<C16;j++)
      #pragma unroll
      for (int r=0;r<4;r++) acc[i][j][r] = 0.f;

  s8v breg[BIT];
  const size_t ar0 = (size_t)(rw + lm)*512 + q*8;
  const size_t ar1 = (size_t)(rw + 16 + lm)*512 + q*8;

  #pragma unroll
  for (int i=0;i<BIT;i++){
    int s = t + i*256;
    if (s < C*4) breg[i] = *(const s8v*)(Xb + (size_t)(s>>2)*512 + (s&3)*8);
  }
  s8v a0 = *(const s8v*)(Mb + ar0);
  s8v a1 = *(const s8v*)(Mb + ar1);

  for (int ks=0; ks<16; ks++){
    #pragma unroll
    for (int i=0;i<BIT;i++){
      int s = t + i*256;
      if (s < C*4) *(s8v*)&Bs[(s>>2)*40 + (s&3)*8] = breg[i];
    }
    __syncthreads();
    const int kn = (ks < 15) ? (ks+1)*32 : 0;
    #pragma unroll
    for (int i=0;i<BIT;i++){
      int s = t + i*256;
      if (s < C*4) breg[i] = *(const s8v*)(Xb + (size_t)(s>>2)*512 + kn + (s&3)*8);
    }
    s8v a0n = *(const s8v*)(Mb + ar0 + kn);
    s8v a1n = *(const s8v*)(Mb + ar1 + kn);
    #pragma unroll
    for (int ct=0; ct<C16; ct++){
      s8v b = *(const s8v*)&Bs[(ct*16+lm)*40 + q*8];
      acc[0][ct] = __builtin_amdgcn_mfma_f32_16x16x32_bf16(a0, b, acc[0][ct], 0,0,0);
      acc[1][ct] = __builtin_amdgcn_mfma_f32_16x16x32_bf16(a1, b, acc[1][ct], 0,0,0);
    }
    __syncthreads();
    a0 = a0n; a1 = a1n;
  }
  #pragma unroll
  for (int rt=0; rt<2; rt++){
    const int m0 = rw + rt*16 + q*4;
    #pragma unroll
    for (int ct=0; ct<C16; ct++){
      const int c = ct*16 + lm;
      u4v o;
      if (BETA){
        u4v y = *(const u4v*)(Yb + (size_t)c*512 + m0);
        #pragma unroll
        for (int r=0;r<4;r++) o[r] = f2b(alpha*acc[rt][ct][r] - b2f(y[r]));
      } else {
        #pragma unroll
        for (int r=0;r<4;r++) o[r] = f2b(acc[rt][ct][r]);
      }
      *(u4v*)(Ob + (size_t)c*512 + m0) = o;
      const size_t rbase = (size_t)(bb*512 + m0)*KP + oseg*C + c;
      #pragma unroll
      for (int r=0;r<4;r++) fR[rbase + (size_t)r*KP] = o[r];
    }
  }
}

template<int KSTEPS, int JT16, int MODE, int HC>
__global__ __launch_bounds__(256) void k_gwB(
    unsigned short* fR, int KP,
    const unsigned short* __restrict__ Wr, const float* __restrict__ bias,
    unsigned short* fC, int C3,
    float* hC, float* rbuf)
{
  constexpr int JT = JT16*16;
  constexpr int BIT = JT*4/256;
  __shared__ unsigned short Bs[JT*40];
  const int t = threadIdx.x;
  const int w = t >> 6, L = t & 63, lm = L & 15, q = L >> 4;
  const int row0 = blockIdx.x * 128;
  const int j0 = blockIdx.y * JT;
  const int rw = row0 + w*32;

  f4v acc[2][JT16];
  #pragma unroll
  for (int i=0;i<2;i++)
    #pragma unroll
    for (int j=0;j<JT16;j++)
      #pragma unroll
      for (int r=0;r<4;r++) acc[i][j][r] = 0.f;

  s8v breg[BIT];
  const unsigned short* Wb = Wr + (size_t)j0*KP;
  const size_t ar0 = (size_t)(rw + lm)*KP + q*8;
  const size_t ar1 = (size_t)(rw + 16 + lm)*KP + q*8;

  #pragma unroll
  for (int i=0;i<BIT;i++){
    int s = t + i*256;
    breg[i] = *(const s8v*)(Wb + (size_t)(s>>2)*KP + (s&3)*8);
  }
  s8v a0 = *(const s8v*)(fR + ar0);
  s8v a1 = *(const s8v*)(fR + ar1);

  for (int ks=0; ks<KSTEPS; ks++){
    #pragma unroll
    for (int i=0;i<BIT;i++){
      int s = t + i*256;
      *(s8v*)&Bs[(s>>2)*40 + (s&3)*8] = breg[i];
    }
    __syncthreads();
    const int kn = (ks < KSTEPS-1) ? (ks+1)*32 : 0;
    #pragma unroll
    for (int i=0;i<BIT;i++){
      int s = t + i*256;
      breg[i] = *(const s8v*)(Wb + (size_t)(s>>2)*KP + kn + (s&3)*8);
    }
    s8v a0n = *(const s8v*)(fR + ar0 + kn);
    s8v a1n = *(const s8v*)(fR + ar1 + kn);
    #pragma unroll
    for (int ct=0; ct<JT16; ct++){
      s8v b = *(const s8v*)&Bs[(ct*16+lm)*40 + q*8];
      acc[0][ct] = __builtin_amdgcn_mfma_f32_16x16x32_bf16(a0, b, acc[0][ct], 0,0,0);
      acc[1][ct] = __builtin_amdgcn_mfma_f32_16x16x32_bf16(a1, b, acc[1][ct], 0,0,0);
    }
    __syncthreads();
    a0 = a0n; a1 = a1n;
  }
  #pragma unroll
  for (int rt=0; rt<2; rt++){
    const int m0 = rw + rt*16 + q*4;
    const int bb = m0 >> 9, n = m0 & 511;
    #pragma unroll
    for (int ct=0; ct<JT16; ct++){
      const int j = j0 + ct*16 + lm;
      const float bj = bias[j];
      if (MODE == 0){
        if (j < HC){
          f4v h4 = *(const f4v*)(hC + ((size_t)bb*HC + j)*512 + n);
          u4v o;
          #pragma unroll
          for (int r=0;r<4;r++){
            float s = 1.f/(1.f + __expf(-(acc[rt][ct][r] + bj)));
            float zh = s * h4[r];
            o[r] = f2b(zh);
            fR[(size_t)(m0+r)*KP + j] = o[r];
          }
          *(u4v*)(fC + ((size_t)bb*C3 + j)*512 + n) = o;
        } else {
          f4v rv;
          #pragma unroll
          for (int r=0;r<4;r++) rv[r] = 1.f/(1.f + __expf(-(acc[rt][ct][r] + bj)));
          *(f4v*)(rbuf + ((size_t)bb*HC + (j-HC))*512 + n) = rv;
        }
      } else {
        f4v h4 = *(const f4v*)(hC + ((size_t)bb*HC + j)*512 + n);
        f4v r4 = *(const f4v*)(rbuf + ((size_t)bb*HC + j)*512 + n);
        u4v o; f4v hn;
        #pragma unroll
        for (int r=0;r<4;r++){
          float e = __expf(2.f*(acc[rt][ct][r] + bj));
          float hc_ = 1.f - 2.f/(e + 1.f);
          hn[r] = r4[r]*h4[r] + (1.f - r4[r])*hc_;
          o[r] = f2b(hn[r]);
          fR[(size_t)(m0+r)*KP + j] = o[r];
        }
        *(f4v*)(hC + ((size_t)bb*HC + j)*512 + n) = hn;
        *(u4v*)(fC + ((size_t)bb*C3 + j)*512 + n) = o;
      }
    }
  }
}

// ======================= glue kernels =======================

__global__ void k_extras_dec(const float* __restrict__ yc,
    unsigned short* fR, unsigned short* fC, int tstep){
  int rr = blockIdx.x*256 + threadIdx.x;   // 32768
  int bb = rr >> 9, n = rr & 511;
  unsigned short u = f2b(yc[((size_t)bb*12 + tstep)*512 + n]);
  fR[(size_t)rr*448 + 129] = u;
  fC[((size_t)bb*432 + 129)*512 + n] = u;
}
__global__ void k_fix_go(unsigned short* fR, unsigned short* fC){
  int rr = blockIdx.x*256 + threadIdx.x;   // 32768
  int bb = rr >> 9, n = rr & 511;
  fR[(size_t)rr*448 + 128] = 0;
  fC[((size_t)bb*432 + 128)*512 + n] = 0;
}

__global__ __launch_bounds__(256) void k_query(const float* __restrict__ hR,
      const float* __restrict__ Wq, const float* __restrict__ Mem,
      float* __restrict__ hCd, unsigned short* fR, unsigned short* fC,
      int* __restrict__ it, int* __restrict__ ih){
  int sub = threadIdx.x >> 6, lane = threadIdx.x & 63;
  int row = blockIdx.x*4 + sub;          // 0..65535
  __shared__ float sh[4][64], sq[4][64], ss[4][20];
  float hv = hR[(size_t)row*64 + lane];
  sh[sub][lane] = hv;
  __syncthreads();
  float qv = 0.f;
  for (int c=0;c<64;c++) qv += sh[sub][c]*Wq[c*64 + lane];
  sq[sub][lane] = qv;
  __syncthreads();
  if (lane < 20){
    float s = 0.f;
    for (int j=0;j<64;j++) s += sq[sub][j]*Mem[lane*64 + j];
    ss[sub][lane] = s;
  }
  __syncthreads();
  float mx = -1e30f; int am = 0;
  for (int m=0;m<20;m++){ float s = ss[sub][m]; if (s > mx){ mx = s; am = m; } }
  float sum = 0.f;
  for (int m=0;m<20;m++) sum += __expf(ss[sub][m]-mx);
  float inv = 1.f/sum;
  float v = 0.f;
  for (int m=0;m<20;m++) v += __expf(ss[sub][m]-mx)*inv*Mem[m*64 + lane];
  int bb = row >> 9, n = row & 511;
  if (bb < 64){
    hCd[((size_t)bb*128 + lane)*512 + n] = hv;
    hCd[((size_t)bb*128 + 64 + lane)*512 + n] = v;
    fR[(size_t)row*448 + lane] = f2b(hv);
    fR[(size_t)row*448 + 64 + lane] = f2b(v);
    fC[((size_t)bb*432 + lane)*512 + n] = f2b(hv);
    fC[((size_t)bb*432 + 64 + lane)*512 + n] = f2b(v);
    if (lane==0) it[row] = am;
  } else {
    if (lane==0) ih[row - 32768] = am;
  }
}

__global__ void k_latent(const int* __restrict__ it, const int* __restrict__ ih,
                         const float* __restrict__ Mem,
                         const float* __restrict__ lW, const float* __restrict__ lb,
                         float* __restrict__ outl){
  int row = blockIdx.x*256 + threadIdx.x;  // 32768
  int i1 = it[row], i2 = ih[row];
  float a = lb[0];
  for (int c=0;c<64;c++) a += (Mem[i1*64+c]-Mem[i2*64+c])*lW[c];
  outl[row] = 1.f/(1.f + __expf(-a));
}

__global__ __launch_bounds__(256) void k_emb(const float* __restrict__ hCd,
    const float* __restrict__ hW, const float* __restrict__ hb, float* __restrict__ emb){
  __shared__ float sW[1280];
  int t = threadIdx.x;
  for (int s=t; s<1280; s+=256) sW[s] = hW[s];
  __syncthreads();
  int rr = blockIdx.x*256 + t;   // 32768
  int bb = rr >> 9, n = rr & 511;
  float a[10];
  #pragma unroll
  for (int e=0;e<10;e++) a[e] = hb[e];
  for (int c=0;c<128;c++){
    float v = hCd[((size_t)bb*128 + c)*512 + n];
    #pragma unroll
    for (int e=0;e<10;e++) a[e] += v*sW[c*10+e];
  }
  #pragma unroll
  for (int e=0;e<10;e++) emb[(size_t)rr*10 + e] = a[e];
}

__global__ __launch_bounds__(256) void k_support(const float* __restrict__ emb,
                                                 unsigned short* __restrict__ sup){
  int b = blockIdx.x >> 9;
  int n = blockIdx.x & 511;
  int t = threadIdx.x;
  __shared__ float se[5120];
  __shared__ float red[8];
  for (int s = t; s < 5120; s += 256) se[s] = emb[(size_t)b*5120 + s];
  __syncthreads();
  float en[10];
  #pragma unroll
  for (int i=0;i<10;i++) en[i] = se[n*10+i];
  float s0=0.f, s1=0.f;
  #pragma unroll
  for (int i=0;i<10;i++){ s0 += en[i]*se[t*10+i]; s1 += en[i]*se[(t+256)*10+i]; }
  s0 = fmaxf(s0, 0.f); s1 = fmaxf(s1, 0.f);
  float mx = fmaxf(s0, s1);
  for (int o=32;o>0;o>>=1) mx = fmaxf(mx, __shfl_down(mx, o));
  if ((t&63)==0) red[t>>6] = mx;
  __syncthreads();
  mx = fmaxf(fmaxf(red[0],red[1]), fmaxf(red[2],red[3]));
  float e0 = __expf(s0-mx), e1 = __expf(s1-mx);
  float sm = e0 + e1;
  for (int o=32;o>0;o>>=1) sm += __shfl_down(sm, o);
  if ((t&63)==0) red[4+(t>>6)] = sm;
  __syncthreads();
  sm = red[4]+red[5]+red[6]+red[7];
  float inv = 1.f/sm;
  size_t base = ((size_t)b*512 + n)*512;
  sup[base + t]       = f2b(e0*inv);
  sup[base + t + 256] = f2b(e1*inv);
}

__global__ __launch_bounds__(256) void k_proj(const float* __restrict__ hCd,
    const float* __restrict__ pW, const float* __restrict__ pb,
    unsigned short* fR, unsigned short* fC, float* __restrict__ out, int tstep){
  __shared__ float sW[128];
  int t = threadIdx.x;
  if (t < 128) sW[t] = pW[t];
  __syncthreads();
  int rr = blockIdx.x*256 + t;   // 32768
  int bb = rr >> 9, n = rr & 511;
  float a = pb[0];
  for (int c=0;c<128;c++) a += hCd[((size_t)bb*128 + c)*512 + n]*sW[c];
  out[((size_t)bb*12 + tstep)*512 + n] = a;
  unsigned short u = f2b(a);
  fR[(size_t)rr*448 + 128] = u;
  fC[((size_t)bb*432 + 128)*512 + n] = u;
}

extern "C" void kernel_launch(void* const* d_in, const int* in_sizes, int n_in,
                              void* d_out, int out_size, void* d_ws, size_t ws_size,
                              hipStream_t stream) {
  const float* x     = (const float*)d_in[0];
  const float* x_his = (const float*)d_in[2];
  const float* y_cov = (const float*)d_in[3];
  const float* adj   = (const float*)d_in[4];
  const float* egW   = (const float*)d_in[5];
  const float* egb   = (const float*)d_in[6];
  const float* euW   = (const float*)d_in[7];
  const float* eub   = (const float*)d_in[8];
  const float* dgW   = (const float*)d_in[9];
  const float* dgb   = (const float*)d_in[10];
  const float* duW   = (const float*)d_in[11];
  const float* dub   = (const float*)d_in[12];
  const float* Mem   = (const float*)d_in[13];
  const float* Wq    = (const float*)d_in[14];
  const float* hW    = (const float*)d_in[15];
  const float* hb    = (const float*)d_in[16];
  const float* lW    = (const float*)d_in[17];
  const float* lb    = (const float*)d_in[18];
  const float* pW    = (const float*)d_in[19];
  const float* pb    = (const float*)d_in[20];
  float* out  = (float*)d_out;           // (64,12,512,1)
  float* outl = out + 393216;            // (64,512)

  char* base = (char*)d_ws;
  size_t off = 0;
  auto alloc = [&](size_t bytes)->char*{
    char* p = base + off; off = (off + bytes + 255) & ~(size_t)255; return p;
  };
  float* featsF = (float*)alloc(53477376);       // 128*512*204 fp32 (encoder)
  //   decoder-phase aliases inside featsF (encoder feats dead by then):
  unsigned short* sup = (unsigned short*)featsF;            // 64*512*512 bf16
  float* emb = featsF + 8650752;                            // 32768*10 fp32
  int*   it  = (int*)(featsF + 9961472);                    // 32768
  int*   ih  = it + 32768;                                  // 32768
  float* henc = (float*)alloc(16777216);         // (128*512)x64 fp32, row-major
  float* zhF  = (float*)alloc(16777216);         // enc z*h (row-major); hCd alias
  float* hCd  = zhF;                             // (64,128,512) fp32 decoder state
  float* rbF  = (float*)alloc(16777216);         // enc r (row-major) / dec r (col-major)
  unsigned short* fR = (unsigned short*)alloc(29360128);  // 32768 x 448 bf16
  unsigned short* fC = (unsigned short*)alloc(28311552);  // 64 x 432 x 512 bf16
  float* a2e = (float*)alloc(1048576);           // 512x512 fp32
  float* wr_egF = (float*)alloc(104448);         // 204x128 fp32
  float* wr_euF = (float*)alloc(52224);          // 204x64 fp32
  unsigned short* wr_dg = (unsigned short*)alloc(229376); // 256x448 bf16
  unsigned short* wr_du = (unsigned short*)alloc(114688); // 128x448 bf16
  if (ws_size < off) return;

  // init (ws is re-poisoned every call)
  k_zero16<<<4096,256,0,stream>>>((uint4*)henc, 1048576);
  k_zero16<<<7168,256,0,stream>>>((uint4*)fR, 1835008);
  k_zero16<<<6912,256,0,stream>>>((uint4*)fC, 1769472);
  k_a2e<<<16,256,0,stream>>>(adj, a2e);
  k_reorderF<<<102,256,0,stream>>>(egW, wr_egF, 64,1,68,128);
  k_reorderF<<< 51,256,0,stream>>>(euW, wr_euF, 64,1,68,64);
  k_reorderB<<<448,256,0,stream>>>(dgW, wr_dg, 128,2,144,448,256);
  k_reorderB<<<224,256,0,stream>>>(duW, wr_du, 128,2,144,448,128);

  // ---------------- fp32 encoders: x | x_his stacked, BB=128 ----------------
  for (int t = 0; t < 12; t++){
    k_mm2F<<<dim3(4,1,128),256,0,stream>>>(adj, a2e, henc, x, x_his, t, featsF);
    k_gwG<<<512,256,0,stream>>>(featsF, wr_egF, egb, henc, zhF, rbF);
    k_mm2F<<<dim3(4,1,128),256,0,stream>>>(adj, a2e, zhF, x, x_his, t, featsF);
    k_gwU<<<512,256,0,stream>>>(featsF, wr_euF, eub, henc, rbF);
  }

  // ---------------- memory query / latent / support (fp32 scores) ----------------
  k_query<<<16384,256,0,stream>>>(henc, Wq, Mem, hCd, fR, fC, it, ih);
  k_latent<<<128,256,0,stream>>>(it, ih, Mem, lW, lb, outl);
  k_emb<<<128,256,0,stream>>>(hCd, hW, hb, emb);
  k_support<<<32768,256,0,stream>>>(emb, sup);
  k_fix_go<<<128,256,0,stream>>>(fR, fC);

  // ---------------- bf16 decoder, BB=64 ----------------
  for (int t = 0; t < 12; t++){
    k_extras_dec<<<128,256,0,stream>>>(y_cov, fR, fC, t);
    k_mmB<9,false><<<dim3(4,1,64),256,0,stream>>>(sup, 262144, fC, 432, 0, 1, fR, 448, 1.f);
    k_mmB<9,true ><<<dim3(4,1,64),256,0,stream>>>(sup, 262144, fC, 432, 1, 2, fR, 448, 2.f);
    k_gwB<14,16,0,128><<<dim3(256,1),256,0,stream>>>(fR, 448, wr_dg, dgb, fC, 432, hCd, rbF);
    k_mmB<9,false><<<dim3(4,1,64),256,0,stream>>>(sup, 262144, fC, 432, 0, 1, fR, 448, 1.f);
    k_mmB<9,true ><<<dim3(4,1,64),256,0,stream>>>(sup, 262144, fC, 432, 1, 2, fR, 448, 2.f);
    k_gwB<14,8,1,128><<<dim3(256,1),256,0,stream>>>(fR, 448, wr_du, dub, fC, 432, hCd, rbF);
    k_proj<<<128,256,0,stream>>>(hCd, pW, pb, fR, fC, out, t);
  }
}